// Round 3
// baseline (214.245 us; speedup 1.0000x reference)
//
#include <hip/hip_runtime.h>
#include <hip/hip_bf16.h>

// WaveletBlock fused kernel (f32 in/out): DWT -> GEMM1(+bias,SiLU) -> GEMM2(+bias) -> IDWT
// R6: TLP-first. R5 post-mortem showed (a) the issue-early staging was nullified by vmcnt
// in-order retirement (GEMM1's first A-fragment wait drained all 32 staged HBM loads), and
// (b) with grid 512 the machine ran at 2 blocks/CU (Occ 20%) with every pipe <25% busy --
// latency-bound from lack of resident waves.
// This version: 32-pixel half-row tiles, grid 2048 (= n16 x hh64 x h2x2), LDS 16.9 KB/block,
// __launch_bounds__(256,8) -> target 8 blocks/CU (32 waves/CU, full occupancy), all 2048
// blocks co-resident in ONE generation. No cross-row staging (no vmcnt hazard); phase-1
// loads interleaved per channel-group (8 loads in flight/thread). All math verbatim R3.
// Cost accepted: weight L2 traffic 2x (524 MB ~ 12 TB/s vs 34.5 TB/s L2 ceiling).

typedef __bf16 bf16x8 __attribute__((ext_vector_type(8)));
typedef float  f32x4  __attribute__((ext_vector_type(4)));

#define SP 264  // LDS row stride in bf16 elems: 528 B = 132 dwords == 4 mod 32 banks;
                // rows stay 16B-aligned for ds_read_b128. GEMM b128 reads are at the
                // conflict-free minimum (8 lanes per distinct 4-bank column).

__device__ __forceinline__ unsigned short f2bf(float f) {
  __hip_bfloat16 h = __float2bfloat16(f);
  return __builtin_bit_cast(unsigned short, h);
}
__device__ __forceinline__ float bf2f(unsigned short s) {
  union { unsigned int i; float f; } v; v.i = ((unsigned int)s) << 16; return v.f;
}
__device__ __forceinline__ float silu(float f) {
  return f / (1.0f + __expf(-f));
}
// Load 8 consecutive f32 weights, convert to a bf16x8 MFMA fragment (fallback path).
__device__ __forceinline__ bf16x8 ldw8(const float* __restrict__ p) {
  const float4 a = *(const float4*)p;
  const float4 b = *(const float4*)(p + 4);
  bf16x8 r;
  r[0] = (__bf16)a.x; r[1] = (__bf16)a.y; r[2] = (__bf16)a.z; r[3] = (__bf16)a.w;
  r[4] = (__bf16)b.x; r[5] = (__bf16)b.y; r[6] = (__bf16)b.z; r[7] = (__bf16)b.w;
  return r;
}

// Prelude: f32 -> bf16 weight conversion into workspace (verbatim R3, no permutation).
__global__ __launch_bounds__(256) void cvt_w(const float* __restrict__ w1,
                                             const float* __restrict__ w2,
                                             unsigned short* __restrict__ o) {
  const int i = (blockIdx.x * 256 + threadIdx.x) * 4;  // grid 64 x 256 covers 65536
  const float4 a = *(const float4*)(w1 + i);
  const float4 b = *(const float4*)(w2 + i);
  *(ushort4*)(o + i)         = make_ushort4(f2bf(a.x), f2bf(a.y), f2bf(a.z), f2bf(a.w));
  *(ushort4*)(o + 65536 + i) = make_ushort4(f2bf(b.x), f2bf(b.y), f2bf(b.z), f2bf(b.w));
}

template <bool WBF16>
__global__ __launch_bounds__(256, 8)
void wavelet_fused(const float* __restrict__ x,
                   const void* __restrict__ w1p,
                   const float* __restrict__ b1,
                   const void* __restrict__ w2p,
                   const float* __restrict__ b2,
                   float* __restrict__ out)
{
  // One buffer, three lives: x_dwt [32 pix][c4] -> feat [32 pix][o] -> y [32 pix][c4].
  __shared__ unsigned short lds[32 * SP];  // 16,896 B => 8 blocks/CU (LDS allows 9)

  const int t  = threadIdx.x;
  const int n  = blockIdx.x >> 7;         // image (b*8+l)
  const int hh = (blockIdx.x >> 1) & 63;  // DWT row
  const int h2 = blockIdx.x & 1;          // half-row (pixel columns 32*h2 .. 32*h2+31)

  const int p  = t & 31;                  // local pixel within half-row (phases 1/4)
  const int cg = t >> 5;                  // channel group 0..7 (8 channels per thread)

  // ---------------- Phase 1: Haar DWT -> lds[p][q*64+c] ----------------
  {
    const float* xb = x + ((size_t)n * 64 * 128 + (size_t)(2 * hh)) * 128
                        + 2 * (32 * h2 + p);
    #pragma unroll
    for (int j = 0; j < 2; ++j) {
      const int c0 = (cg + 8 * j) * 4;
      float qv[4][4];
      #pragma unroll
      for (int ci = 0; ci < 4; ++ci) {
        const float* pp = xb + (size_t)(c0 + ci) * (128 * 128);
        const float2 r0 = *(const float2*)pp;          // x[2hh,   2ww], x[2hh,   2ww+1]
        const float2 r1 = *(const float2*)(pp + 128);  // x[2hh+1, 2ww], x[2hh+1, 2ww+1]
        const float x1 = r0.x, x3 = r0.y;              // even row: even col, odd col
        const float x2 = r1.x, x4 = r1.y;              // odd  row: even col, odd col
        qv[0][ci] = 0.5f * ((x1 + x2) + (x3 + x4));
        qv[1][ci] = 0.5f * ((x3 + x4) - (x1 + x2));
        qv[2][ci] = 0.5f * ((x2 + x4) - (x1 + x3));
        qv[3][ci] = 0.5f * ((x1 + x4) - (x2 + x3));
      }
      #pragma unroll
      for (int q = 0; q < 4; ++q) {
        ushort4 v = make_ushort4(f2bf(qv[q][0]), f2bf(qv[q][1]), f2bf(qv[q][2]), f2bf(qv[q][3]));
        *(ushort4*)(&lds[p * SP + q * 64 + c0]) = v;
      }
    }
  }
  __syncthreads();

  const int wv   = t >> 6;        // wave id: o-slice / c4-slice of 64 rows
  const int r    = t & 15;        // MFMA row/col-in-tile
  const int quad = (t & 63) >> 4; // MFMA quad: k-offset (inputs) / row-offset (output)

  // ---------------- Phase 2: GEMM1  D[o][pix] = conv_w . x_dwt;  silu -> lds[pix][o] ----------------
  {
    f32x4 acc[4][2];
    #pragma unroll
    for (int mt = 0; mt < 4; ++mt)
      #pragma unroll
      for (int nt = 0; nt < 2; ++nt)
        acc[mt][nt] = (f32x4){0.0f, 0.0f, 0.0f, 0.0f};

    #pragma unroll
    for (int k0 = 0; k0 < 256; k0 += 32) {
      bf16x8 a[4], b[2];
      #pragma unroll
      for (int mt = 0; mt < 4; ++mt) {  // A: conv_w rows o (L2-resident)
        const int row = wv * 64 + mt * 16 + r;
        if constexpr (WBF16)
          a[mt] = *(const bf16x8*)((const unsigned short*)w1p + row * 256 + quad * 8 + k0);
        else
          a[mt] = ldw8((const float*)w1p + row * 256 + quad * 8 + k0);
      }
      #pragma unroll
      for (int nt = 0; nt < 2; ++nt)   // B: x_dwt[pix][k] (ds_read_b128)
        b[nt] = *(const bf16x8*)(&lds[(nt * 16 + r) * SP + quad * 8 + k0]);
      #pragma unroll
      for (int mt = 0; mt < 4; ++mt)
        #pragma unroll
        for (int nt = 0; nt < 2; ++nt)
          acc[mt][nt] = __builtin_amdgcn_mfma_f32_16x16x32_bf16(a[mt], b[nt], acc[mt][nt], 0, 0, 0);
    }
    __syncthreads();  // all GEMM1 reads of lds done

    // Epilogue: lane holds 4 consecutive o (rows) at col pix -> b64 LDS write
    #pragma unroll
    for (int mt = 0; mt < 4; ++mt) {
      const int ob = wv * 64 + mt * 16 + quad * 4;
      const float4 bb = *(const float4*)(b1 + ob);
      #pragma unroll
      for (int nt = 0; nt < 2; ++nt) {
        const int pix = nt * 16 + r;
        ushort4 v;
        v.x = f2bf(silu(acc[mt][nt][0] + bb.x));
        v.y = f2bf(silu(acc[mt][nt][1] + bb.y));
        v.z = f2bf(silu(acc[mt][nt][2] + bb.z));
        v.w = f2bf(silu(acc[mt][nt][3] + bb.w));
        *(ushort4*)(&lds[pix * SP + ob]) = v;
      }
    }
  }
  __syncthreads();

  // ---------------- Phase 3: GEMM2  D[c4][pix] = conv_out_w . feat -> lds[pix][c4] ----------------
  {
    f32x4 acc[4][2];
    #pragma unroll
    for (int mt = 0; mt < 4; ++mt)
      #pragma unroll
      for (int nt = 0; nt < 2; ++nt)
        acc[mt][nt] = (f32x4){0.0f, 0.0f, 0.0f, 0.0f};

    #pragma unroll
    for (int k0 = 0; k0 < 256; k0 += 32) {
      bf16x8 a[4], b[2];
      #pragma unroll
      for (int mt = 0; mt < 4; ++mt) {  // A: conv_out_w rows c4
        const int row = wv * 64 + mt * 16 + r;
        if constexpr (WBF16)
          a[mt] = *(const bf16x8*)((const unsigned short*)w2p + row * 256 + quad * 8 + k0);
        else
          a[mt] = ldw8((const float*)w2p + row * 256 + quad * 8 + k0);
      }
      #pragma unroll
      for (int nt = 0; nt < 2; ++nt)   // B: feat[pix][o]
        b[nt] = *(const bf16x8*)(&lds[(nt * 16 + r) * SP + quad * 8 + k0]);
      #pragma unroll
      for (int mt = 0; mt < 4; ++mt)
        #pragma unroll
        for (int nt = 0; nt < 2; ++nt)
          acc[mt][nt] = __builtin_amdgcn_mfma_f32_16x16x32_bf16(a[mt], b[nt], acc[mt][nt], 0, 0, 0);
    }
    __syncthreads();  // all GEMM2 reads of lds done

    #pragma unroll
    for (int mt = 0; mt < 4; ++mt) {
      const int cb = wv * 64 + mt * 16 + quad * 4;
      const float4 bb = *(const float4*)(b2 + cb);
      #pragma unroll
      for (int nt = 0; nt < 2; ++nt) {
        const int pix = nt * 16 + r;
        ushort4 v;
        v.x = f2bf(acc[mt][nt][0] + bb.x);
        v.y = f2bf(acc[mt][nt][1] + bb.y);
        v.z = f2bf(acc[mt][nt][2] + bb.z);
        v.w = f2bf(acc[mt][nt][3] + bb.w);
        *(ushort4*)(&lds[pix * SP + cb]) = v;
      }
    }
  }
  __syncthreads();

  // ---------------- Phase 4: IDWT + coalesced float2 stores ----------------
  {
    float* ob_ = out + ((size_t)n * 64 * 128 + (size_t)(2 * hh)) * 128
                     + 2 * (32 * h2 + p);
    #pragma unroll
    for (int j = 0; j < 2; ++j) {
      const int c0 = (cg + 8 * j) * 4;
      unsigned short yb[4][4];
      #pragma unroll
      for (int q = 0; q < 4; ++q) {
        const ushort4 v = *(const ushort4*)(&lds[p * SP + q * 64 + c0]);
        yb[q][0] = v.x; yb[q][1] = v.y; yb[q][2] = v.z; yb[q][3] = v.w;
      }
      #pragma unroll
      for (int ci = 0; ci < 4; ++ci) {
        const float y1 = 0.5f * bf2f(yb[0][ci]);
        const float y2 = 0.5f * bf2f(yb[1][ci]);
        const float y3 = 0.5f * bf2f(yb[2][ci]);
        const float y4 = 0.5f * bf2f(yb[3][ci]);
        const float s14 = y1 + y4, s23 = y2 + y3;
        const float d14 = y1 - y4, d23 = y2 - y3;
        const float oa  = s14 - s23;  // (2hh,   2ww)
        const float oc  = d14 + d23;  // (2hh,   2ww+1)
        const float obv = d14 - d23;  // (2hh+1, 2ww)
        const float od  = s14 + s23;  // (2hh+1, 2ww+1)
        float* prow = ob_ + (size_t)(c0 + ci) * (128 * 128);
        *(float2*)prow         = make_float2(oa, oc);
        *(float2*)(prow + 128) = make_float2(obv, od);
      }
    }
  }
}

extern "C" void kernel_launch(void* const* d_in, const int* in_sizes, int n_in,
                              void* d_out, int out_size, void* d_ws, size_t ws_size,
                              hipStream_t stream) {
  (void)in_sizes; (void)n_in; (void)out_size;
  const float* x  = (const float*)d_in[0];
  const float* w1 = (const float*)d_in[1];
  const float* b1 = (const float*)d_in[2];
  const float* w2 = (const float*)d_in[3];
  const float* b2 = (const float*)d_in[4];
  float* o = (float*)d_out;

  if (ws_size >= 2u * 65536u * sizeof(unsigned short)) {
    unsigned short* wb = (unsigned short*)d_ws;
    cvt_w<<<dim3(64), dim3(256), 0, stream>>>(w1, w2, wb);
    wavelet_fused<true><<<dim3(16 * 64 * 2), dim3(256), 0, stream>>>(
        x, wb, b1, wb + 65536, b2, o);
  } else {
    wavelet_fused<false><<<dim3(16 * 64 * 2), dim3(256), 0, stream>>>(
        x, w1, b1, w2, b2, o);
  }
}

// Round 4
// 173.608 us; speedup vs baseline: 1.2341x; 1.2341x over previous
//
#include <hip/hip_runtime.h>
#include <hip/hip_bf16.h>

// WaveletBlock fused kernel (f32 in/out): DWT -> GEMM1(+bias,SiLU) -> GEMM2(+bias) -> IDWT
// R7: high occupancy WITHOUT spills. R6 post-mortem: launch_bounds(256,8) forced VGPR=32
// vs ~100 needed -> ~125 MB scratch traffic (FETCH 35->73 MB, WRITE 65->152 MB), dur 2x.
// Fix is structural: shrink per-WAVE state instead of forcing the allocator.
//   - 512-thread blocks (8 waves); each wave owns a 32-row o/c4-slice: acc[2][2]=16 VGPR,
//     a[2]+b[2]=16, addrs ~8 -> ~50-70 peak, fits launch_bounds(512,6) cap (~84) spill-free;
//     if regalloc lands <=64 we get 8 waves/EU (100% occupancy).
//   - 32-pixel half-row tiles, grid 2048, LDS 16.9 KB/block -> LDS never binds.
//   - All math verbatim R3/R6 (harness-verified); only thread geometry changes.

typedef __bf16 bf16x8 __attribute__((ext_vector_type(8)));
typedef float  f32x4  __attribute__((ext_vector_type(4)));

#define SP 264  // LDS row stride in bf16 elems: 528 B = 132 dwords == 4 mod 32 banks;
                // rows stay 16B-aligned for ds_read_b128. GEMM b128 reads <=2-way.

__device__ __forceinline__ unsigned short f2bf(float f) {
  __hip_bfloat16 h = __float2bfloat16(f);
  return __builtin_bit_cast(unsigned short, h);
}
__device__ __forceinline__ float bf2f(unsigned short s) {
  union { unsigned int i; float f; } v; v.i = ((unsigned int)s) << 16; return v.f;
}
__device__ __forceinline__ float silu(float f) {
  return f / (1.0f + __expf(-f));
}
// Load 8 consecutive f32 weights, convert to a bf16x8 MFMA fragment (fallback path).
__device__ __forceinline__ bf16x8 ldw8(const float* __restrict__ p) {
  const float4 a = *(const float4*)p;
  const float4 b = *(const float4*)(p + 4);
  bf16x8 r;
  r[0] = (__bf16)a.x; r[1] = (__bf16)a.y; r[2] = (__bf16)a.z; r[3] = (__bf16)a.w;
  r[4] = (__bf16)b.x; r[5] = (__bf16)b.y; r[6] = (__bf16)b.z; r[7] = (__bf16)b.w;
  return r;
}

// Prelude: f32 -> bf16 weight conversion into workspace (verbatim R3, no permutation).
__global__ __launch_bounds__(256) void cvt_w(const float* __restrict__ w1,
                                             const float* __restrict__ w2,
                                             unsigned short* __restrict__ o) {
  const int i = (blockIdx.x * 256 + threadIdx.x) * 4;  // grid 64 x 256 covers 65536
  const float4 a = *(const float4*)(w1 + i);
  const float4 b = *(const float4*)(w2 + i);
  *(ushort4*)(o + i)         = make_ushort4(f2bf(a.x), f2bf(a.y), f2bf(a.z), f2bf(a.w));
  *(ushort4*)(o + 65536 + i) = make_ushort4(f2bf(b.x), f2bf(b.y), f2bf(b.z), f2bf(b.w));
}

template <bool WBF16>
__global__ __launch_bounds__(512, 6)
void wavelet_fused(const float* __restrict__ x,
                   const void* __restrict__ w1p,
                   const float* __restrict__ b1,
                   const void* __restrict__ w2p,
                   const float* __restrict__ b2,
                   float* __restrict__ out)
{
  // One buffer, three lives: x_dwt [32 pix][c4] -> feat [32 pix][o] -> y [32 pix][c4].
  __shared__ unsigned short lds[32 * SP];  // 16,896 B

  const int t  = threadIdx.x;
  const int n  = blockIdx.x >> 7;         // image (b*8+l)
  const int hh = (blockIdx.x >> 1) & 63;  // DWT row
  const int h2 = blockIdx.x & 1;          // half-row (pixel columns 32*h2 .. 32*h2+31)

  const int p  = t & 31;                  // local pixel within half-row (phases 1/4)
  const int cg = t >> 5;                  // channel group 0..15 (4 channels per thread)

  // ---------------- Phase 1: Haar DWT -> lds[p][q*64+c] ----------------
  {
    const float* xb = x + ((size_t)n * 64 * 128 + (size_t)(2 * hh)) * 128
                        + 2 * (32 * h2 + p);
    const int c0 = cg * 4;
    float qv[4][4];
    #pragma unroll
    for (int ci = 0; ci < 4; ++ci) {
      const float* pp = xb + (size_t)(c0 + ci) * (128 * 128);
      const float2 r0 = *(const float2*)pp;          // x[2hh,   2ww], x[2hh,   2ww+1]
      const float2 r1 = *(const float2*)(pp + 128);  // x[2hh+1, 2ww], x[2hh+1, 2ww+1]
      const float x1 = r0.x, x3 = r0.y;              // even row: even col, odd col
      const float x2 = r1.x, x4 = r1.y;              // odd  row: even col, odd col
      qv[0][ci] = 0.5f * ((x1 + x2) + (x3 + x4));
      qv[1][ci] = 0.5f * ((x3 + x4) - (x1 + x2));
      qv[2][ci] = 0.5f * ((x2 + x4) - (x1 + x3));
      qv[3][ci] = 0.5f * ((x1 + x4) - (x2 + x3));
    }
    #pragma unroll
    for (int q = 0; q < 4; ++q) {
      ushort4 v = make_ushort4(f2bf(qv[q][0]), f2bf(qv[q][1]), f2bf(qv[q][2]), f2bf(qv[q][3]));
      *(ushort4*)(&lds[p * SP + q * 64 + c0]) = v;
    }
  }
  __syncthreads();

  const int wv   = t >> 6;        // wave id 0..7: 32-row o-slice / c4-slice
  const int r    = t & 15;        // MFMA row/col-in-tile
  const int quad = (t & 63) >> 4; // MFMA quad: k-offset (inputs) / row-offset (output)

  // ---------------- Phase 2: GEMM1  D[o][pix] = conv_w . x_dwt;  silu -> lds[pix][o] ----------------
  {
    f32x4 acc[2][2];
    #pragma unroll
    for (int mt = 0; mt < 2; ++mt)
      #pragma unroll
      for (int nt = 0; nt < 2; ++nt)
        acc[mt][nt] = (f32x4){0.0f, 0.0f, 0.0f, 0.0f};

    #pragma unroll
    for (int k0 = 0; k0 < 256; k0 += 32) {
      bf16x8 a[2], b[2];
      #pragma unroll
      for (int mt = 0; mt < 2; ++mt) {  // A: conv_w rows o (L2-resident)
        const int row = wv * 32 + mt * 16 + r;
        if constexpr (WBF16)
          a[mt] = *(const bf16x8*)((const unsigned short*)w1p + row * 256 + quad * 8 + k0);
        else
          a[mt] = ldw8((const float*)w1p + row * 256 + quad * 8 + k0);
      }
      #pragma unroll
      for (int nt = 0; nt < 2; ++nt)   // B: x_dwt[pix][k] (ds_read_b128)
        b[nt] = *(const bf16x8*)(&lds[(nt * 16 + r) * SP + quad * 8 + k0]);
      #pragma unroll
      for (int mt = 0; mt < 2; ++mt)
        #pragma unroll
        for (int nt = 0; nt < 2; ++nt)
          acc[mt][nt] = __builtin_amdgcn_mfma_f32_16x16x32_bf16(a[mt], b[nt], acc[mt][nt], 0, 0, 0);
    }
    __syncthreads();  // all GEMM1 reads of lds done

    // Epilogue: lane holds 4 consecutive o (rows) at col pix -> b64 LDS write
    #pragma unroll
    for (int mt = 0; mt < 2; ++mt) {
      const int ob = wv * 32 + mt * 16 + quad * 4;
      const float4 bb = *(const float4*)(b1 + ob);
      #pragma unroll
      for (int nt = 0; nt < 2; ++nt) {
        const int pix = nt * 16 + r;
        ushort4 v;
        v.x = f2bf(silu(acc[mt][nt][0] + bb.x));
        v.y = f2bf(silu(acc[mt][nt][1] + bb.y));
        v.z = f2bf(silu(acc[mt][nt][2] + bb.z));
        v.w = f2bf(silu(acc[mt][nt][3] + bb.w));
        *(ushort4*)(&lds[pix * SP + ob]) = v;
      }
    }
  }
  __syncthreads();

  // ---------------- Phase 3: GEMM2  D[c4][pix] = conv_out_w . feat -> lds[pix][c4] ----------------
  {
    f32x4 acc[2][2];
    #pragma unroll
    for (int mt = 0; mt < 2; ++mt)
      #pragma unroll
      for (int nt = 0; nt < 2; ++nt)
        acc[mt][nt] = (f32x4){0.0f, 0.0f, 0.0f, 0.0f};

    #pragma unroll
    for (int k0 = 0; k0 < 256; k0 += 32) {
      bf16x8 a[2], b[2];
      #pragma unroll
      for (int mt = 0; mt < 2; ++mt) {  // A: conv_out_w rows c4
        const int row = wv * 32 + mt * 16 + r;
        if constexpr (WBF16)
          a[mt] = *(const bf16x8*)((const unsigned short*)w2p + row * 256 + quad * 8 + k0);
        else
          a[mt] = ldw8((const float*)w2p + row * 256 + quad * 8 + k0);
      }
      #pragma unroll
      for (int nt = 0; nt < 2; ++nt)   // B: feat[pix][o]
        b[nt] = *(const bf16x8*)(&lds[(nt * 16 + r) * SP + quad * 8 + k0]);
      #pragma unroll
      for (int mt = 0; mt < 2; ++mt)
        #pragma unroll
        for (int nt = 0; nt < 2; ++nt)
          acc[mt][nt] = __builtin_amdgcn_mfma_f32_16x16x32_bf16(a[mt], b[nt], acc[mt][nt], 0, 0, 0);
    }
    __syncthreads();  // all GEMM2 reads of lds done

    #pragma unroll
    for (int mt = 0; mt < 2; ++mt) {
      const int cb = wv * 32 + mt * 16 + quad * 4;
      const float4 bb = *(const float4*)(b2 + cb);
      #pragma unroll
      for (int nt = 0; nt < 2; ++nt) {
        const int pix = nt * 16 + r;
        ushort4 v;
        v.x = f2bf(acc[mt][nt][0] + bb.x);
        v.y = f2bf(acc[mt][nt][1] + bb.y);
        v.z = f2bf(acc[mt][nt][2] + bb.z);
        v.w = f2bf(acc[mt][nt][3] + bb.w);
        *(ushort4*)(&lds[pix * SP + cb]) = v;
      }
    }
  }
  __syncthreads();

  // ---------------- Phase 4: IDWT + coalesced float2 stores ----------------
  {
    float* ob_ = out + ((size_t)n * 64 * 128 + (size_t)(2 * hh)) * 128
                     + 2 * (32 * h2 + p);
    const int c0 = cg * 4;
    unsigned short yb[4][4];
    #pragma unroll
    for (int q = 0; q < 4; ++q) {
      const ushort4 v = *(const ushort4*)(&lds[p * SP + q * 64 + c0]);
      yb[q][0] = v.x; yb[q][1] = v.y; yb[q][2] = v.z; yb[q][3] = v.w;
    }
    #pragma unroll
    for (int ci = 0; ci < 4; ++ci) {
      const float y1 = 0.5f * bf2f(yb[0][ci]);
      const float y2 = 0.5f * bf2f(yb[1][ci]);
      const float y3 = 0.5f * bf2f(yb[2][ci]);
      const float y4 = 0.5f * bf2f(yb[3][ci]);
      const float s14 = y1 + y4, s23 = y2 + y3;
      const float d14 = y1 - y4, d23 = y2 - y3;
      const float oa  = s14 - s23;  // (2hh,   2ww)
      const float oc  = d14 + d23;  // (2hh,   2ww+1)
      const float obv = d14 - d23;  // (2hh+1, 2ww)
      const float od  = s14 + s23;  // (2hh+1, 2ww+1)
      float* prow = ob_ + (size_t)(c0 + ci) * (128 * 128);
      *(float2*)prow         = make_float2(oa, oc);
      *(float2*)(prow + 128) = make_float2(obv, od);
    }
  }
}

extern "C" void kernel_launch(void* const* d_in, const int* in_sizes, int n_in,
                              void* d_out, int out_size, void* d_ws, size_t ws_size,
                              hipStream_t stream) {
  (void)in_sizes; (void)n_in; (void)out_size;
  const float* x  = (const float*)d_in[0];
  const float* w1 = (const float*)d_in[1];
  const float* b1 = (const float*)d_in[2];
  const float* w2 = (const float*)d_in[3];
  const float* b2 = (const float*)d_in[4];
  float* o = (float*)d_out;

  if (ws_size >= 2u * 65536u * sizeof(unsigned short)) {
    unsigned short* wb = (unsigned short*)d_ws;
    cvt_w<<<dim3(64), dim3(256), 0, stream>>>(w1, w2, wb);
    wavelet_fused<true><<<dim3(16 * 64 * 2), dim3(512), 0, stream>>>(
        x, wb, b1, wb + 65536, b2, o);
  } else {
    wavelet_fused<false><<<dim3(16 * 64 * 2), dim3(512), 0, stream>>>(
        x, w1, b1, w2, b2, o);
  }
}

// Round 6
// 147.057 us; speedup vs baseline: 1.4569x; 1.1806x over previous
//
#include <hip/hip_runtime.h>
#include <hip/hip_bf16.h>

// WaveletBlock fused kernel (f32 in/out): DWT -> GEMM1(+bias,SiLU) -> GEMM2(+bias) -> IDWT
// R9 = R5 (harness-verified, 62us/dispatch) with ONE change: all __syncthreads() replaced
// by LDS-only barriers (s_waitcnt lgkmcnt(0); s_barrier).
// Why: __syncthreads() compiles to s_waitcnt vmcnt(0) lgkmcnt(0) before s_barrier, which
// (a) drains the 32 staged row-1 x-loads at the GEMM1-epilogue barrier -> the issue-early
//     pipeline never overlapped anything (R5 post-mortem), and
// (b) forces each row's 64KB of output stores to fully retire while all 8 waves idle at
//     the next barrier (~5us/row of serial HBM time).
// Every barrier in this kernel only protects LDS write->read / read->overwrite edges, so
// lgkmcnt(0) is sufficient; global loads land in private VGPRs (compiler inserts vmcnt
// waits at first use) and global stores are to disjoint, never-re-read memory.
// The "memory" clobber fences compiler reordering of LDS/global ops across the barrier.
// Fused-IDWT epilogue (R4/R8) is abandoned: failed harness twice despite derivation.

typedef __bf16 bf16x8 __attribute__((ext_vector_type(8)));
typedef float  f32x4  __attribute__((ext_vector_type(4)));

#define SP 264  // LDS row stride in bf16 elems: 528 B = 132 dwords == 4 mod 32 banks;
                // rows stay 16B-aligned for ds_read_b128. GEMM-phase accesses are <=2-way.

__device__ __forceinline__ void barrier_lds() {
  // LDS-visibility barrier WITHOUT vmcnt drain (unlike __syncthreads).
  asm volatile("s_waitcnt lgkmcnt(0)\n\ts_barrier" ::: "memory");
}

__device__ __forceinline__ unsigned short f2bf(float f) {
  __hip_bfloat16 h = __float2bfloat16(f);
  return __builtin_bit_cast(unsigned short, h);
}
__device__ __forceinline__ float bf2f(unsigned short s) {
  union { unsigned int i; float f; } v; v.i = ((unsigned int)s) << 16; return v.f;
}
__device__ __forceinline__ float silu(float f) {
  return f / (1.0f + __expf(-f));
}
// Load 8 consecutive f32 weights, convert to a bf16x8 MFMA fragment (fallback path).
__device__ __forceinline__ bf16x8 ldw8(const float* __restrict__ p) {
  const float4 a = *(const float4*)p;
  const float4 b = *(const float4*)(p + 4);
  bf16x8 r;
  r[0] = (__bf16)a.x; r[1] = (__bf16)a.y; r[2] = (__bf16)a.z; r[3] = (__bf16)a.w;
  r[4] = (__bf16)b.x; r[5] = (__bf16)b.y; r[6] = (__bf16)b.z; r[7] = (__bf16)b.w;
  return r;
}

// Prelude: f32 -> bf16 weight conversion into workspace (verbatim R3, no permutation).
__global__ __launch_bounds__(256) void cvt_w(const float* __restrict__ w1,
                                             const float* __restrict__ w2,
                                             unsigned short* __restrict__ o) {
  const int i = (blockIdx.x * 256 + threadIdx.x) * 4;  // grid 64 x 256 covers 65536
  const float4 a = *(const float4*)(w1 + i);
  const float4 b = *(const float4*)(w2 + i);
  *(ushort4*)(o + i)         = make_ushort4(f2bf(a.x), f2bf(a.y), f2bf(a.z), f2bf(a.w));
  *(ushort4*)(o + 65536 + i) = make_ushort4(f2bf(b.x), f2bf(b.y), f2bf(b.z), f2bf(b.w));
}

// Phase-1a: issue one row's x loads into registers (thread t handles pixel ww = t&63,
// channel groups cg = t>>6; 32x float2 = 64 VGPRs).
__device__ __forceinline__ void load_st(const float* __restrict__ x, int n, int hh,
                                        int ww, int cg, float2 (&st)[32]) {
  const float* xb = x + ((size_t)n * 64 * 128 + (size_t)(2 * hh)) * 128 + 2 * ww;
  #pragma unroll
  for (int j = 0; j < 4; ++j) {
    const int c0 = (cg + 4 * j) * 4;
    #pragma unroll
    for (int ci = 0; ci < 4; ++ci) {
      const float* p = xb + (size_t)(c0 + ci) * (128 * 128);
      st[(j * 4 + ci) * 2]     = *(const float2*)p;          // x[2hh,   2ww], x[2hh,   2ww+1]
      st[(j * 4 + ci) * 2 + 1] = *(const float2*)(p + 128);  // x[2hh+1, 2ww], x[2hh+1, 2ww+1]
    }
  }
}

// Phase-1b: Haar DWT of staged regs -> lds[ww][q*64+c] as bf16 (verbatim R5 math/writes).
__device__ __forceinline__ void dwt_write(const float2 (&st)[32], unsigned short* lds,
                                          int ww, int cg) {
  #pragma unroll
  for (int j = 0; j < 4; ++j) {
    const int c0 = (cg + 4 * j) * 4;
    float qv[4][4];
    #pragma unroll
    for (int ci = 0; ci < 4; ++ci) {
      const float2 r0 = st[(j * 4 + ci) * 2];
      const float2 r1 = st[(j * 4 + ci) * 2 + 1];
      const float x1 = r0.x, x3 = r0.y;  // even row: even col, odd col
      const float x2 = r1.x, x4 = r1.y;  // odd  row: even col, odd col
      qv[0][ci] = 0.5f * ((x1 + x2) + (x3 + x4));
      qv[1][ci] = 0.5f * ((x3 + x4) - (x1 + x2));
      qv[2][ci] = 0.5f * ((x2 + x4) - (x1 + x3));
      qv[3][ci] = 0.5f * ((x1 + x4) - (x2 + x3));
    }
    #pragma unroll
    for (int q = 0; q < 4; ++q) {
      ushort4 v = make_ushort4(f2bf(qv[q][0]), f2bf(qv[q][1]), f2bf(qv[q][2]), f2bf(qv[q][3]));
      *(ushort4*)(&lds[ww * SP + q * 64 + c0]) = v;
    }
  }
}

// Phases 2-4 for one row (verbatim R5 math; barriers are LDS-only).
template <bool WBF16>
__device__ __forceinline__ void process_row(unsigned short* lds,
                                            const void* __restrict__ w1p,
                                            const float* __restrict__ b1,
                                            const void* __restrict__ w2p,
                                            const float* __restrict__ b2,
                                            float* __restrict__ out, int n, int hh,
                                            int t, int ww, int cg) {
  const int wv   = t >> 6;        // wave id: o-slice / c4-slice of 64 rows
  const int r    = t & 15;        // MFMA row/col-in-tile
  const int quad = (t & 63) >> 4; // MFMA quad: k-offset (inputs) / row-offset (output)

  // ---------------- Phase 2: GEMM1  D[o][pix] = conv_w . x_dwt;  silu -> lds[pix][o] ----------------
  {
    f32x4 acc[4][4];
    #pragma unroll
    for (int mt = 0; mt < 4; ++mt)
      #pragma unroll
      for (int nt = 0; nt < 4; ++nt)
        acc[mt][nt] = (f32x4){0.0f, 0.0f, 0.0f, 0.0f};

    #pragma unroll
    for (int k0 = 0; k0 < 256; k0 += 32) {
      bf16x8 a[4], b[4];
      #pragma unroll
      for (int mt = 0; mt < 4; ++mt) {  // A: conv_w rows o (L2-resident)
        const int row = wv * 64 + mt * 16 + r;
        if constexpr (WBF16)
          a[mt] = *(const bf16x8*)((const unsigned short*)w1p + row * 256 + quad * 8 + k0);
        else
          a[mt] = ldw8((const float*)w1p + row * 256 + quad * 8 + k0);
      }
      #pragma unroll
      for (int nt = 0; nt < 4; ++nt)   // B: x_dwt[pix][k] (ds_read_b128)
        b[nt] = *(const bf16x8*)(&lds[(nt * 16 + r) * SP + quad * 8 + k0]);
      #pragma unroll
      for (int mt = 0; mt < 4; ++mt)
        #pragma unroll
        for (int nt = 0; nt < 4; ++nt)
          acc[mt][nt] = __builtin_amdgcn_mfma_f32_16x16x32_bf16(a[mt], b[nt], acc[mt][nt], 0, 0, 0);
    }
    barrier_lds();  // all GEMM1 LDS reads done (staged row-loads stay in flight)

    // Epilogue: lane holds 4 consecutive o (rows) at col pix -> b64 LDS write
    #pragma unroll
    for (int mt = 0; mt < 4; ++mt) {
      const int ob = wv * 64 + mt * 16 + quad * 4;
      const float4 bb = *(const float4*)(b1 + ob);
      #pragma unroll
      for (int nt = 0; nt < 4; ++nt) {
        const int pix = nt * 16 + r;
        ushort4 v;
        v.x = f2bf(silu(acc[mt][nt][0] + bb.x));
        v.y = f2bf(silu(acc[mt][nt][1] + bb.y));
        v.z = f2bf(silu(acc[mt][nt][2] + bb.z));
        v.w = f2bf(silu(acc[mt][nt][3] + bb.w));
        *(ushort4*)(&lds[pix * SP + ob]) = v;
      }
    }
  }
  barrier_lds();  // feat visible

  // ---------------- Phase 3: GEMM2  D[c4][pix] = conv_out_w . feat -> lds[pix][c4] ----------------
  {
    f32x4 acc[4][4];
    #pragma unroll
    for (int mt = 0; mt < 4; ++mt)
      #pragma unroll
      for (int nt = 0; nt < 4; ++nt)
        acc[mt][nt] = (f32x4){0.0f, 0.0f, 0.0f, 0.0f};

    #pragma unroll
    for (int k0 = 0; k0 < 256; k0 += 32) {
      bf16x8 a[4], b[4];
      #pragma unroll
      for (int mt = 0; mt < 4; ++mt) {  // A: conv_out_w rows c4
        const int row = wv * 64 + mt * 16 + r;
        if constexpr (WBF16)
          a[mt] = *(const bf16x8*)((const unsigned short*)w2p + row * 256 + quad * 8 + k0);
        else
          a[mt] = ldw8((const float*)w2p + row * 256 + quad * 8 + k0);
      }
      #pragma unroll
      for (int nt = 0; nt < 4; ++nt)   // B: feat[pix][o]
        b[nt] = *(const bf16x8*)(&lds[(nt * 16 + r) * SP + quad * 8 + k0]);
      #pragma unroll
      for (int mt = 0; mt < 4; ++mt)
        #pragma unroll
        for (int nt = 0; nt < 4; ++nt)
          acc[mt][nt] = __builtin_amdgcn_mfma_f32_16x16x32_bf16(a[mt], b[nt], acc[mt][nt], 0, 0, 0);
    }
    barrier_lds();  // all GEMM2 LDS reads done

    #pragma unroll
    for (int mt = 0; mt < 4; ++mt) {
      const int cb = wv * 64 + mt * 16 + quad * 4;
      const float4 bb = *(const float4*)(b2 + cb);
      #pragma unroll
      for (int nt = 0; nt < 4; ++nt) {
        const int pix = nt * 16 + r;
        ushort4 v;
        v.x = f2bf(acc[mt][nt][0] + bb.x);
        v.y = f2bf(acc[mt][nt][1] + bb.y);
        v.z = f2bf(acc[mt][nt][2] + bb.z);
        v.w = f2bf(acc[mt][nt][3] + bb.w);
        *(ushort4*)(&lds[pix * SP + cb]) = v;
      }
    }
  }
  barrier_lds();  // y visible

  // ---------------- Phase 4: IDWT + coalesced float2 stores (fly across later barriers) ----------------
  {
    float* ob_ = out + ((size_t)n * 64 * 128 + (size_t)(2 * hh)) * 128 + 2 * ww;
    #pragma unroll
    for (int j = 0; j < 4; ++j) {
      const int c0 = (cg + 4 * j) * 4;
      unsigned short yb[4][4];
      #pragma unroll
      for (int q = 0; q < 4; ++q) {
        const ushort4 v = *(const ushort4*)(&lds[ww * SP + q * 64 + c0]);
        yb[q][0] = v.x; yb[q][1] = v.y; yb[q][2] = v.z; yb[q][3] = v.w;
      }
      #pragma unroll
      for (int ci = 0; ci < 4; ++ci) {
        const float y1 = 0.5f * bf2f(yb[0][ci]);
        const float y2 = 0.5f * bf2f(yb[1][ci]);
        const float y3 = 0.5f * bf2f(yb[2][ci]);
        const float y4 = 0.5f * bf2f(yb[3][ci]);
        const float s14 = y1 + y4, s23 = y2 + y3;
        const float d14 = y1 - y4, d23 = y2 - y3;
        const float oa  = s14 - s23;  // (2hh,   2ww)
        const float oc  = d14 + d23;  // (2hh,   2ww+1)
        const float obv = d14 - d23;  // (2hh+1, 2ww)
        const float od  = s14 + s23;  // (2hh+1, 2ww+1)
        float* prow = ob_ + (size_t)(c0 + ci) * (128 * 128);
        *(float2*)prow         = make_float2(oa, oc);
        *(float2*)(prow + 128) = make_float2(obv, od);
      }
    }
  }
}

template <bool WBF16>
__global__ __launch_bounds__(256, 2)
void wavelet_fused(const float* __restrict__ x,
                   const void* __restrict__ w1p,
                   const float* __restrict__ b1,
                   const void* __restrict__ w2p,
                   const float* __restrict__ b2,
                   float* __restrict__ out)
{
  // One buffer, three lives per row: x_dwt [pix][c4] -> feat [pix][o] -> y [pix][c4].
  __shared__ unsigned short lds[64 * SP];  // 33,792 B

  const int t  = threadIdx.x;
  const int ww = t & 63;            // pixel column for phases 1/4 (lane-contiguous -> coalesced)
  const int cg = t >> 6;

  const int idx0 = blockIdx.x;            // rows 0..511   (images 0..7)
  const int idx1 = blockIdx.x + 512;      // rows 512..1023 (images 8..15)
  const int n0 = idx0 >> 6, hh0 = idx0 & 63;
  const int n1 = idx1 >> 6, hh1 = idx1 & 63;

  float2 st[32];  // 64-VGPR staging: row i+1's x in flight across row i's GEMMs

  // ---- row 0: load + DWT ----
  load_st(x, n0, hh0, ww, cg, st);
  dwt_write(st, lds, ww, cg);
  barrier_lds();                   // B1: x_dwt(row0) visible

  // issue row 1's loads NOW; with LDS-only barriers they genuinely stay in flight
  // across row-0's GEMM phases (no vmcnt(0) drain at any barrier).
  load_st(x, n1, hh1, ww, cg, st);

  process_row<WBF16>(lds, w1p, b1, w2p, b2, out, n0, hh0, t, ww, cg);

  barrier_lds();                   // B6: phase-4 row-0 LDS reads done before overwrite
  dwt_write(st, lds, ww, cg);      // row-1 DWT into freed buffer
  barrier_lds();                   // B7: x_dwt(row1) visible

  process_row<WBF16>(lds, w1p, b1, w2p, b2, out, n1, hh1, t, ww, cg);
}

extern "C" void kernel_launch(void* const* d_in, const int* in_sizes, int n_in,
                              void* d_out, int out_size, void* d_ws, size_t ws_size,
                              hipStream_t stream) {
  (void)in_sizes; (void)n_in; (void)out_size;
  const float* x  = (const float*)d_in[0];
  const float* w1 = (const float*)d_in[1];
  const float* b1 = (const float*)d_in[2];
  const float* w2 = (const float*)d_in[3];
  const float* b2 = (const float*)d_in[4];
  float* o = (float*)d_out;

  if (ws_size >= 2u * 65536u * sizeof(unsigned short)) {
    unsigned short* wb = (unsigned short*)d_ws;
    cvt_w<<<dim3(64), dim3(256), 0, stream>>>(w1, w2, wb);
    wavelet_fused<true><<<dim3(512), dim3(256), 0, stream>>>(
        x, wb, b1, wb + 65536, b2, o);
  } else {
    wavelet_fused<false><<<dim3(512), dim3(256), 0, stream>>>(
        x, w1, b1, w2, b2, o);
  }
}

// Round 7
// 146.158 us; speedup vs baseline: 1.4658x; 1.0062x over previous
//
#include <hip/hip_runtime.h>
#include <hip/hip_bf16.h>

// WaveletBlock fused kernel (f32 in/out): DWT -> GEMM1(+bias,SiLU) -> GEMM2(+bias) -> IDWT
// R10 = R9 (verified, ~61us/dispatch) + memory-PATTERN changes only:
//  (a) 16B/lane global access: phase-1 loads float4 (R4 mapping u=t&31,g=t>>5 --
//      re-verified; R8 proved R4's bug was the W2-perm, not this), phase-4 float4 stores
//      (2 pixels/thread). Halves global instruction count, doubles segment size.
//  (b) XCD-chunked block swizzle (T1, bijective: grid 512 = 8 XCD x 64): xcd=bid&7 owns
//      hh in [8*xcd, 8*xcd+8) for all images -> each XCD streams contiguous 8KB spans
//      per channel plane instead of every-8th-KB shreds.
// Rationale: R3/R5/R7/R9 show dur invariant to occupancy (20-54%), barrier semantics,
// and pipelining, while hbm_gbps is flat at ~2 TB/s -> pattern-limited memory bound.
// GEMM phases, epilogues, LDS-only barriers, 2-row pipeline: verbatim R9.

typedef __bf16 bf16x8 __attribute__((ext_vector_type(8)));
typedef float  f32x4  __attribute__((ext_vector_type(4)));
typedef unsigned short u16x8 __attribute__((ext_vector_type(8)));

#define SP 264  // LDS row stride in bf16 elems: 528 B = 132 dwords == 4 mod 32 banks;
                // rows stay 16B-aligned for ds_read_b128. GEMM-phase accesses are <=2-way;
                // phase-1/4 b128 accesses alias 8-way = the 8-cycle hardware minimum.

__device__ __forceinline__ void barrier_lds() {
  // LDS-visibility barrier WITHOUT vmcnt drain (unlike __syncthreads).
  asm volatile("s_waitcnt lgkmcnt(0)\n\ts_barrier" ::: "memory");
}

__device__ __forceinline__ unsigned short f2bf(float f) {
  __hip_bfloat16 h = __float2bfloat16(f);
  return __builtin_bit_cast(unsigned short, h);
}
__device__ __forceinline__ float bf2f(unsigned short s) {
  union { unsigned int i; float f; } v; v.i = ((unsigned int)s) << 16; return v.f;
}
__device__ __forceinline__ float silu(float f) {
  return f / (1.0f + __expf(-f));
}
// Load 8 consecutive f32 weights, convert to a bf16x8 MFMA fragment (fallback path).
__device__ __forceinline__ bf16x8 ldw8(const float* __restrict__ p) {
  const float4 a = *(const float4*)p;
  const float4 b = *(const float4*)(p + 4);
  bf16x8 r;
  r[0] = (__bf16)a.x; r[1] = (__bf16)a.y; r[2] = (__bf16)a.z; r[3] = (__bf16)a.w;
  r[4] = (__bf16)b.x; r[5] = (__bf16)b.y; r[6] = (__bf16)b.z; r[7] = (__bf16)b.w;
  return r;
}

// Prelude: f32 -> bf16 weight conversion into workspace (verbatim R3, no permutation).
__global__ __launch_bounds__(256) void cvt_w(const float* __restrict__ w1,
                                             const float* __restrict__ w2,
                                             unsigned short* __restrict__ o) {
  const int i = (blockIdx.x * 256 + threadIdx.x) * 4;  // grid 64 x 256 covers 65536
  const float4 a = *(const float4*)(w1 + i);
  const float4 b = *(const float4*)(w2 + i);
  *(ushort4*)(o + i)         = make_ushort4(f2bf(a.x), f2bf(a.y), f2bf(a.z), f2bf(a.w));
  *(ushort4*)(o + 65536 + i) = make_ushort4(f2bf(b.x), f2bf(b.y), f2bf(b.z), f2bf(b.w));
}

// Phase-1a: issue one row's x loads as float4 (16B/lane): thread t (u=t&31, g=t>>5)
// loads cols 4u..4u+3 of rows 2hh/2hh+1 for channels g*8..g*8+7. 16x dwordx4 = 64 VGPRs.
__device__ __forceinline__ void load_st(const float* __restrict__ x, int n, int hh,
                                        int u, int g, float4 (&st)[16]) {
  const float* xb = x + ((size_t)n * 64 * 128 + (size_t)(2 * hh)) * 128 + 4 * u;
  #pragma unroll
  for (int i = 0; i < 8; ++i) {
    const float* p = xb + (size_t)(g * 8 + i) * (128 * 128);
    st[2 * i]     = *(const float4*)p;          // row 2hh,   cols 4u..4u+3
    st[2 * i + 1] = *(const float4*)(p + 128);  // row 2hh+1, cols 4u..4u+3
  }
}

// Phase-1b: Haar DWT of staged regs -> lds[pix][q*64+c] as bf16, pixels 2u and 2u+1.
// 8x ds_write_b128; lane addr stride 8 banks + half-wave +4 -> 8-way = 8-cycle minimum.
__device__ __forceinline__ void dwt_write(const float4 (&st)[16], unsigned short* lds,
                                          int u, int g) {
  u16x8 v[4][2];
  #pragma unroll
  for (int i = 0; i < 8; ++i) {
    const float4 r0 = st[2 * i];
    const float4 r1 = st[2 * i + 1];
    #pragma unroll
    for (int p = 0; p < 2; ++p) {
      const float x1 = p ? r0.z : r0.x;  // even row, even col
      const float x3 = p ? r0.w : r0.y;  // even row, odd col
      const float x2 = p ? r1.z : r1.x;  // odd row,  even col
      const float x4 = p ? r1.w : r1.y;  // odd row,  odd col
      v[0][p][i] = f2bf(0.5f * ((x1 + x2) + (x3 + x4)));
      v[1][p][i] = f2bf(0.5f * ((x3 + x4) - (x1 + x2)));
      v[2][p][i] = f2bf(0.5f * ((x2 + x4) - (x1 + x3)));
      v[3][p][i] = f2bf(0.5f * ((x1 + x4) - (x2 + x3)));
    }
  }
  #pragma unroll
  for (int p = 0; p < 2; ++p)
    #pragma unroll
    for (int q = 0; q < 4; ++q)
      *(u16x8*)(&lds[(2 * u + p) * SP + q * 64 + g * 8]) = v[q][p];
}

// Phases 2-4 for one row (GEMM math verbatim R9; phase-4 is the float4 mirror of phase-1).
template <bool WBF16>
__device__ __forceinline__ void process_row(unsigned short* lds,
                                            const void* __restrict__ w1p,
                                            const float* __restrict__ b1,
                                            const void* __restrict__ w2p,
                                            const float* __restrict__ b2,
                                            float* __restrict__ out, int n, int hh,
                                            int t, int u, int g) {
  const int wv   = t >> 6;        // wave id: o-slice / c4-slice of 64 rows
  const int r    = t & 15;        // MFMA row/col-in-tile
  const int quad = (t & 63) >> 4; // MFMA quad: k-offset (inputs) / row-offset (output)

  // ---------------- Phase 2: GEMM1  D[o][pix] = conv_w . x_dwt;  silu -> lds[pix][o] ----------------
  {
    f32x4 acc[4][4];
    #pragma unroll
    for (int mt = 0; mt < 4; ++mt)
      #pragma unroll
      for (int nt = 0; nt < 4; ++nt)
        acc[mt][nt] = (f32x4){0.0f, 0.0f, 0.0f, 0.0f};

    #pragma unroll
    for (int k0 = 0; k0 < 256; k0 += 32) {
      bf16x8 a[4], b[4];
      #pragma unroll
      for (int mt = 0; mt < 4; ++mt) {  // A: conv_w rows o (L2-resident)
        const int row = wv * 64 + mt * 16 + r;
        if constexpr (WBF16)
          a[mt] = *(const bf16x8*)((const unsigned short*)w1p + row * 256 + quad * 8 + k0);
        else
          a[mt] = ldw8((const float*)w1p + row * 256 + quad * 8 + k0);
      }
      #pragma unroll
      for (int nt = 0; nt < 4; ++nt)   // B: x_dwt[pix][k] (ds_read_b128)
        b[nt] = *(const bf16x8*)(&lds[(nt * 16 + r) * SP + quad * 8 + k0]);
      #pragma unroll
      for (int mt = 0; mt < 4; ++mt)
        #pragma unroll
        for (int nt = 0; nt < 4; ++nt)
          acc[mt][nt] = __builtin_amdgcn_mfma_f32_16x16x32_bf16(a[mt], b[nt], acc[mt][nt], 0, 0, 0);
    }
    barrier_lds();  // all GEMM1 LDS reads done (staged row-loads stay in flight)

    // Epilogue: lane holds 4 consecutive o (rows) at col pix -> b64 LDS write
    #pragma unroll
    for (int mt = 0; mt < 4; ++mt) {
      const int ob = wv * 64 + mt * 16 + quad * 4;
      const float4 bb = *(const float4*)(b1 + ob);
      #pragma unroll
      for (int nt = 0; nt < 4; ++nt) {
        const int pix = nt * 16 + r;
        ushort4 v;
        v.x = f2bf(silu(acc[mt][nt][0] + bb.x));
        v.y = f2bf(silu(acc[mt][nt][1] + bb.y));
        v.z = f2bf(silu(acc[mt][nt][2] + bb.z));
        v.w = f2bf(silu(acc[mt][nt][3] + bb.w));
        *(ushort4*)(&lds[pix * SP + ob]) = v;
      }
    }
  }
  barrier_lds();  // feat visible

  // ---------------- Phase 3: GEMM2  D[c4][pix] = conv_out_w . feat -> lds[pix][c4] ----------------
  {
    f32x4 acc[4][4];
    #pragma unroll
    for (int mt = 0; mt < 4; ++mt)
      #pragma unroll
      for (int nt = 0; nt < 4; ++nt)
        acc[mt][nt] = (f32x4){0.0f, 0.0f, 0.0f, 0.0f};

    #pragma unroll
    for (int k0 = 0; k0 < 256; k0 += 32) {
      bf16x8 a[4], b[4];
      #pragma unroll
      for (int mt = 0; mt < 4; ++mt) {  // A: conv_out_w rows c4
        const int row = wv * 64 + mt * 16 + r;
        if constexpr (WBF16)
          a[mt] = *(const bf16x8*)((const unsigned short*)w2p + row * 256 + quad * 8 + k0);
        else
          a[mt] = ldw8((const float*)w2p + row * 256 + quad * 8 + k0);
      }
      #pragma unroll
      for (int nt = 0; nt < 4; ++nt)   // B: feat[pix][o]
        b[nt] = *(const bf16x8*)(&lds[(nt * 16 + r) * SP + quad * 8 + k0]);
      #pragma unroll
      for (int mt = 0; mt < 4; ++mt)
        #pragma unroll
        for (int nt = 0; nt < 4; ++nt)
          acc[mt][nt] = __builtin_amdgcn_mfma_f32_16x16x32_bf16(a[mt], b[nt], acc[mt][nt], 0, 0, 0);
    }
    barrier_lds();  // all GEMM2 LDS reads done

    #pragma unroll
    for (int mt = 0; mt < 4; ++mt) {
      const int cb = wv * 64 + mt * 16 + quad * 4;
      const float4 bb = *(const float4*)(b2 + cb);
      #pragma unroll
      for (int nt = 0; nt < 4; ++nt) {
        const int pix = nt * 16 + r;
        ushort4 v;
        v.x = f2bf(acc[mt][nt][0] + bb.x);
        v.y = f2bf(acc[mt][nt][1] + bb.y);
        v.z = f2bf(acc[mt][nt][2] + bb.z);
        v.w = f2bf(acc[mt][nt][3] + bb.w);
        *(ushort4*)(&lds[pix * SP + cb]) = v;
      }
    }
  }
  barrier_lds();  // y visible

  // ---------------- Phase 4: IDWT + float4 stores (2 pixels/thread, 16B/lane) ----------------
  {
    float* ob_ = out + ((size_t)n * 64 * 128 + (size_t)(2 * hh)) * 128 + 4 * u;
    u16x8 yq[2][4];
    #pragma unroll
    for (int p = 0; p < 2; ++p)
      #pragma unroll
      for (int q = 0; q < 4; ++q)
        yq[p][q] = *(const u16x8*)(&lds[(2 * u + p) * SP + q * 64 + g * 8]);
    #pragma unroll
    for (int i = 0; i < 8; ++i) {
      float4 e, o;  // output rows 2hh (even) and 2hh+1 (odd), cols 4u..4u+3
      #pragma unroll
      for (int p = 0; p < 2; ++p) {
        const float y1 = 0.5f * bf2f(yq[p][0][i]);
        const float y2 = 0.5f * bf2f(yq[p][1][i]);
        const float y3 = 0.5f * bf2f(yq[p][2][i]);
        const float y4 = 0.5f * bf2f(yq[p][3][i]);
        const float s14 = y1 + y4, s23 = y2 + y3;
        const float d14 = y1 - y4, d23 = y2 - y3;
        if (p == 0) { e.x = s14 - s23; e.y = d14 + d23; o.x = d14 - d23; o.y = s14 + s23; }
        else        { e.z = s14 - s23; e.w = d14 + d23; o.z = d14 - d23; o.w = s14 + s23; }
      }
      float* prow = ob_ + (size_t)(g * 8 + i) * (128 * 128);
      *(float4*)prow         = e;
      *(float4*)(prow + 128) = o;
    }
  }
}

template <bool WBF16>
__global__ __launch_bounds__(256, 2)
void wavelet_fused(const float* __restrict__ x,
                   const void* __restrict__ w1p,
                   const float* __restrict__ b1,
                   const void* __restrict__ w2p,
                   const float* __restrict__ b2,
                   float* __restrict__ out)
{
  // One buffer, three lives per row: x_dwt [pix][c4] -> feat [pix][o] -> y [pix][c4].
  __shared__ unsigned short lds[64 * SP];  // 33,792 B

  const int t = threadIdx.x;
  const int u = t & 31;             // 4-col group (pixels 2u, 2u+1) for phases 1/4
  const int g = t >> 5;             // 8-channel group for phases 1/4

  // XCD-chunked swizzle (bijective, grid 512 = 8 x 64): xcd owns hh in [8*xcd, 8*xcd+8)
  // for all images -> contiguous 16 h-rows (8KB) per channel plane per XCD.
  const int xcd = blockIdx.x & 7;
  const int k   = blockIdx.x >> 3;        // 0..63
  const int n0  = k & 7;                  // images 0..7 (row 0)
  const int hh  = (xcd << 3) | (k >> 3);  // DWT row
  const int n1  = n0 + 8;                 // images 8..15 (row 1), same hh

  float4 st[16];  // 64-VGPR staging: row i+1's x in flight across row i's GEMMs

  // ---- row 0: load + DWT ----
  load_st(x, n0, hh, u, g, st);
  dwt_write(st, lds, u, g);
  barrier_lds();                   // B1: x_dwt(row0) visible

  // issue row 1's loads NOW; with LDS-only barriers they stay in flight across
  // row-0's GEMM phases (no vmcnt(0) drain at any barrier).
  load_st(x, n1, hh, u, g, st);

  process_row<WBF16>(lds, w1p, b1, w2p, b2, out, n0, hh, t, u, g);

  barrier_lds();                   // B6: phase-4 row-0 LDS reads done before overwrite
  dwt_write(st, lds, u, g);        // row-1 DWT into freed buffer
  barrier_lds();                   // B7: x_dwt(row1) visible

  process_row<WBF16>(lds, w1p, b1, w2p, b2, out, n1, hh, t, u, g);
}

extern "C" void kernel_launch(void* const* d_in, const int* in_sizes, int n_in,
                              void* d_out, int out_size, void* d_ws, size_t ws_size,
                              hipStream_t stream) {
  (void)in_sizes; (void)n_in; (void)out_size;
  const float* x  = (const float*)d_in[0];
  const float* w1 = (const float*)d_in[1];
  const float* b1 = (const float*)d_in[2];
  const float* w2 = (const float*)d_in[3];
  const float* b2 = (const float*)d_in[4];
  float* o = (float*)d_out;

  if (ws_size >= 2u * 65536u * sizeof(unsigned short)) {
    unsigned short* wb = (unsigned short*)d_ws;
    cvt_w<<<dim3(64), dim3(256), 0, stream>>>(w1, w2, wb);
    wavelet_fused<true><<<dim3(512), dim3(256), 0, stream>>>(
        x, wb, b1, wb + 65536, b2, o);
  } else {
    wavelet_fused<false><<<dim3(512), dim3(256), 0, stream>>>(
        x, w1, b1, w2, b2, o);
  }
}